// Round 4
// baseline (313.812 us; speedup 1.0000x reference)
//
#include <hip/hip_runtime.h>

#define NN 20000

typedef _Float16 f16x4 __attribute__((ext_vector_type(4)));

// ---------------- softmax of W (single block) ----------------
__global__ __launch_bounds__(1024) void softmax_kernel(const float* __restrict__ W,
                                                       float* __restrict__ pi,
                                                       float* __restrict__ pi1,
                                                       float* __restrict__ pi2) {
    __shared__ float red[1024];
    __shared__ float piL[4096];
    int t = threadIdx.x;
    float4 wv = ((const float4*)W)[t];
    float m = fmaxf(fmaxf(wv.x, wv.y), fmaxf(wv.z, wv.w));
    red[t] = m; __syncthreads();
    for (int s = 512; s > 0; s >>= 1) {
        if (t < s) red[t] = fmaxf(red[t], red[t + s]);
        __syncthreads();
    }
    m = red[0];
    __syncthreads();
    float e0 = expf(wv.x - m), e1 = expf(wv.y - m);
    float e2 = expf(wv.z - m), e3 = expf(wv.w - m);
    red[t] = e0 + e1 + e2 + e3;
    __syncthreads();
    for (int s = 512; s > 0; s >>= 1) {
        if (t < s) red[t] += red[t + s];
        __syncthreads();
    }
    float inv = 1.0f / red[0];
    piL[t * 4 + 0] = e0 * inv;
    piL[t * 4 + 1] = e1 * inv;
    piL[t * 4 + 2] = e2 * inv;
    piL[t * 4 + 3] = e3 * inv;
    pi[t * 4 + 0] = e0 * inv;
    pi[t * 4 + 1] = e1 * inv;
    pi[t * 4 + 2] = e2 * inv;
    pi[t * 4 + 3] = e3 * inv;
    __syncthreads();
    if (t < 64) {            // row sums -> pi1 (weights for F1)
        float s = 0.f;
        for (int k = 0; k < 64; k++) s += piL[t * 64 + k];
        pi1[t] = s;
    } else if (t < 128) {    // col sums -> pi2 (weights for F2)
        int k = t - 64;
        float s = 0.f;
        for (int j = 0; j < 64; j++) s += piL[j * 64 + k];
        pi2[k] = s;
    }
}

// ---------------- expand packed f16x4 finals -> fp32 (B,N) planes ----------------
// SINGLE block: all reads complete before any write (src overlaps plane b=3).
__global__ __launch_bounds__(1024) void expand_kernel(const f16x4* __restrict__ src,
                                                      float* __restrict__ out) {
    int t = threadIdx.x;
    f16x4 v[20];
#pragma unroll
    for (int i = 0; i < 20; i++) {
        int idx = i * 1024 + t;
        if (idx < NN) v[i] = src[idx];
    }
    __syncthreads();
#pragma unroll
    for (int i = 0; i < 20; i++) {
        int idx = i * 1024 + t;
        if (idx < NN) {
            out[idx] = (float)v[i][0];
            out[NN + idx] = (float)v[i][1];
            out[2 * NN + idx] = (float)v[i][2];
            out[3 * NN + idx] = (float)v[i][3];
        }
    }
}

// ---------------- per-iteration kernel ----------------
// Block = 1024 threads = 64 groups of 16 lanes. Group handles one n (all 4 b).
// Lane l owns j,k in {4l..4l+3}. Whole a (f16x4 per n, 4 batches) in 160,000 B
// static LDS (gfx950 group segment is 160 KiB — R2 compiled & loaded fine).
// X1/X2 are INT32 (harness converts all integer inputs to int32!):
// flat layout ((k*NN+n)*8 + w)*2 + {0,1}; per (k,n) that is 16 consecutive
// int32 = 64 B = 4 x int4 loads.
__device__ __forceinline__ void compute_F(const int* __restrict__ X,
                                          const f16x4* __restrict__ aldsv,
                                          int n, int l, float4 pw,
                                          float Ff[4][4], float acc[4]) {
#pragma unroll
    for (int kk = 0; kk < 4; ++kk) {
        int k = l * 4 + kk;
        const int4* xq = (const int4*)X + ((size_t)k * NN + n) * 4;
        f16x4 fm = { (_Float16)0, (_Float16)0, (_Float16)0, (_Float16)0 };
#pragma unroll
        for (int ww = 0; ww < 4; ++ww) {
            int4 q = xq[ww];                 // 2 (idx0,idx1) pairs
            f16x4 g0 = aldsv[q.x];
            f16x4 g1 = aldsv[q.y];
            f16x4 g2 = aldsv[q.z];
            f16x4 g3 = aldsv[q.w];
            fm = __builtin_elementwise_max(fm, g0 * g1);
            fm = __builtin_elementwise_max(fm, g2 * g3);
        }
        float pk = (kk == 0) ? pw.x : (kk == 1) ? pw.y : (kk == 2) ? pw.z : pw.w;
#pragma unroll
        for (int b = 0; b < 4; b++) {
            float f = (float)fm[b];
            Ff[kk][b] = f;
            acc[b] += pk * f;
        }
    }
}

// SRC16: 0 = stage LDS table from a0 fp32 (B,N) planes; 1 = from packed f16x4.
// DST16: 1 = write packed f16x4; 0 = write fp32 (B,N) planes.
template <int SRC16, int DST16>
__global__ __launch_bounds__(1024) void iter_kernel(
    const float* __restrict__ asrc, const f16x4* __restrict__ asrc16,
    const int* __restrict__ X1, const int* __restrict__ X2,
    const float* __restrict__ pi, const float* __restrict__ pi1,
    const float* __restrict__ pi2,
    float* __restrict__ dst, f16x4* __restrict__ dst16) {
    __shared__ f16x4 aldsv[NN];  // 160,000 B
    int tid = threadIdx.x;

    if (SRC16) {
        for (int i = tid; i < NN; i += 1024) aldsv[i] = asrc16[i];
    } else {
        for (int i = tid; i < NN; i += 1024) {
            f16x4 h = { (_Float16)asrc[i], (_Float16)asrc[NN + i],
                        (_Float16)asrc[2 * NN + i], (_Float16)asrc[3 * NN + i] };
            aldsv[i] = h;
        }
    }
    __syncthreads();  // no barriers after this point

    int l = tid & 15;
    int g = tid >> 4;
    int n = blockIdx.x * 64 + g;
    if (n >= NN) return;

    float4 p1v = ((const float4*)pi1)[l];
    float4 p2v = ((const float4*)pi2)[l];

    float F1f[4][4], F2f[4][4];
    float A1[4] = {0, 0, 0, 0}, Ev[4] = {0, 0, 0, 0}, A2[4] = {0, 0, 0, 0};

    compute_F(X2, aldsv, n, l, p2v, F2f, Ev);
    compute_F(X1, aldsv, n, l, p1v, F1f, A1);

    // Euv partial: sum over all j, lane-owned k of pi[j,k]*F1[j]*F2[k]
    for (int jo = 0; jo < 16; jo++) {
#pragma unroll
        for (int ji = 0; ji < 4; ji++) {
            int j = jo * 4 + ji;
            float4 pr = ((const float4*)(pi + j * 64))[l];
#pragma unroll
            for (int b = 0; b < 4; b++) {
                float f1 = __shfl(F1f[ji][b], jo, 16);
                float t = pr.x * F2f[0][b] + pr.y * F2f[1][b] +
                          pr.z * F2f[2][b] + pr.w * F2f[3][b];
                A2[b] += f1 * t;
            }
        }
    }

    float s[4];
#pragma unroll
    for (int b = 0; b < 4; b++) s[b] = A1[b] + Ev[b] - A2[b];
#pragma unroll
    for (int off = 8; off >= 1; off >>= 1) {
#pragma unroll
        for (int b = 0; b < 4; b++) s[b] += __shfl_xor(s[b], off, 16);
    }

    if (l == 0) {
        float a[4];
        if (SRC16) {
            f16x4 h = aldsv[n];  // a after previous iter (f16-rounded, ok)
#pragma unroll
            for (int b = 0; b < 4; b++) a[b] = (float)h[b];
        } else {
#pragma unroll
            for (int b = 0; b < 4; b++) a[b] = asrc[(size_t)b * NN + n];  // exact a0
        }
#pragma unroll
        for (int b = 0; b < 4; b++) s[b] = 1.0f - (1.0f - a[b]) * (1.0f - s[b]);
        if (DST16) {
            f16x4 h = { (_Float16)s[0], (_Float16)s[1], (_Float16)s[2], (_Float16)s[3] };
            dst16[n] = h;
        } else {
            dst[n] = s[0];
            dst[NN + n] = s[1];
            dst[2 * NN + n] = s[2];
            dst[3 * NN + n] = s[3];
        }
    }
}

extern "C" void kernel_launch(void* const* d_in, const int* in_sizes, int n_in,
                              void* d_out, int out_size, void* d_ws, size_t ws_size,
                              hipStream_t stream) {
    const float* a0 = (const float*)d_in[0];
    const float* W = (const float*)d_in[1];
    const int* X1 = (const int*)d_in[2];   // int64 in reference -> int32 on device
    const int* X2 = (const int*)d_in[3];
    float* out = (float*)d_out;
    const int grid = (NN + 63) / 64;       // 313

    const bool use_ws = (ws_size >= (size_t)177408);
    if (use_ws) {
        // ws: pi @0 (16384B), pi1 @16384, pi2 @16640, a1 packed f16x4 @17408
        float* pi = (float*)d_ws;
        float* pi1 = pi + 4096;
        float* pi2 = pi1 + 64;
        f16x4* at1 = (f16x4*)((char*)d_ws + 17408);
        softmax_kernel<<<1, 1024, 0, stream>>>(W, pi, pi1, pi2);
        iter_kernel<0, 1><<<grid, 1024, 0, stream>>>(a0, nullptr, X1, X2,
                                                     pi, pi1, pi2, nullptr, at1);
        iter_kernel<1, 0><<<grid, 1024, 0, stream>>>(nullptr, at1, X1, X2,
                                                     pi, pi1, pi2, out, nullptr);
    } else {
        // d_out (320,000B) as scratch: pi @0..17408, a1 @80,000..240,000,
        // finals packed @240,000..320,000; expand overwrites everything last.
        float* pi = (float*)d_out;
        float* pi1 = pi + 4096;
        float* pi2 = pi1 + 64;
        f16x4* at1 = (f16x4*)((char*)d_out + 80000);
        f16x4* fin = (f16x4*)((char*)d_out + 240000);
        softmax_kernel<<<1, 1024, 0, stream>>>(W, pi, pi1, pi2);
        iter_kernel<0, 1><<<grid, 1024, 0, stream>>>(a0, nullptr, X1, X2,
                                                     pi, pi1, pi2, nullptr, at1);
        iter_kernel<1, 1><<<grid, 1024, 0, stream>>>(nullptr, at1, X1, X2,
                                                     pi, pi1, pi2, nullptr, fin);
        expand_kernel<<<1, 1024, 0, stream>>>(fin, out);
    }
}